// Round 4
// baseline (475.408 us; speedup 1.0000x reference)
//
#include <hip/hip_runtime.h>
#include <math.h>

// Problem constants
#define NROWS 65536
#define DDIM  1024
#define NEXP  64
#define BM    64      // rows per block
#define BK    32      // K chunk (== one MFMA K)
#define NK    (DDIM / BK)
#define WCHUNK 12288  // shorts per k32-chunk of packed w: 3 splits * 128 n * 32 k

typedef short bf16x8 __attribute__((ext_vector_type(8)));
typedef float f32x4  __attribute__((ext_vector_type(4)));
typedef unsigned int u32x4 __attribute__((ext_vector_type(4)));

// exact-ish 3-way bf16 split, round-to-nearest (used in one-time w prep)
__device__ __forceinline__ void split3(float x, unsigned short& h,
                                       unsigned short& m, unsigned short& l) {
    unsigned u = __float_as_uint(x);
    unsigned r = u + 0x7FFFu + ((u >> 16) & 1u);
    h = (unsigned short)(r >> 16);
    float hf = __uint_as_float(r & 0xFFFF0000u);
    float r1 = x - hf;
    unsigned u2 = __float_as_uint(r1);
    unsigned r2 = u2 + 0x7FFFu + ((u2 >> 16) & 1u);
    m = (unsigned short)(r2 >> 16);
    float mf = __uint_as_float(r2 & 0xFFFF0000u);
    float r3 = r1 - mf;
    unsigned u3 = __float_as_uint(r3);
    unsigned r4 = u3 + 0x7FFFu + ((u3 >> 16) & 1u);
    l = (unsigned short)(r4 >> 16);
}

__device__ __forceinline__ float softplus_f(float x) {
    return fmaxf(x, 0.0f) + log1pf(expf(-fabsf(x)));
}

// Pack weights: wp[chunk][split][n][32] bf16, n = 0..63 route, 64..127 noise.
__global__ void __launch_bounds__(256) prep_w_kernel(
        const float* __restrict__ wr, const float* __restrict__ wn,
        short* __restrict__ wp) {
    int idx = blockIdx.x * 256 + threadIdx.x;   // 0..131071
    int n = idx >> 10;
    int k = idx & 1023;
    float v = (n < NEXP) ? wr[n * DDIM + k] : wn[(n - NEXP) * DDIM + k];
    unsigned short h, m, l;
    split3(v, h, m, l);
    int base = (k >> 5) * WCHUNK + n * 32 + (k & 31);
    wp[base]        = (short)h;
    wp[base + 4096] = (short)m;
    wp[base + 8192] = (short)l;
}

// truncation split of 8 k-consecutive fp32 into three bf16x8 MFMA A-fragments.
// Bit-identical limbs to the staged split3t path: h=trunc16(x), m=trunc16(x-h),
// l=trunc16(x-h-m). Packing via v_perm_b32 (1 op per bf16 pair per limb).
__device__ __forceinline__ void split_pack(const f32x4 a, const f32x4 b,
                                           bf16x8& H, bf16x8& M, bf16x8& L) {
    float f[8];
    *(f32x4*)&f[0] = a;
    *(f32x4*)&f[4] = b;
    u32x4 hp, mp, lp;
#pragma unroll
    for (int j = 0; j < 4; ++j) {
        float x0 = f[2 * j], x1 = f[2 * j + 1];
        unsigned u0 = __float_as_uint(x0), u1 = __float_as_uint(x1);
        hp[j] = __builtin_amdgcn_perm(u1, u0, 0x07060302u);   // [x1.hi16 : x0.hi16]
        float r0 = x0 - __uint_as_float(u0 & 0xFFFF0000u);
        float r1 = x1 - __uint_as_float(u1 & 0xFFFF0000u);
        unsigned v0 = __float_as_uint(r0), v1 = __float_as_uint(r1);
        mp[j] = __builtin_amdgcn_perm(v1, v0, 0x07060302u);
        float s0 = r0 - __uint_as_float(v0 & 0xFFFF0000u);
        float s1 = r1 - __uint_as_float(v1 & 0xFFFF0000u);
        lp[j] = __builtin_amdgcn_perm(__float_as_uint(s1), __float_as_uint(s0),
                                      0x07060302u);
    }
    H = *(bf16x8*)&hp;
    M = *(bf16x8*)&mp;
    L = *(bf16x8*)&lp;
}

__device__ __forceinline__ void top2_merge(float& v0, int& i0, float& v1, int& i1,
                                           float pv0, int pi0, float pv1, int pi1) {
    bool t0 = (pv0 > v0) || (pv0 == v0 && pi0 < i0);
    if (t0) {
        bool t1 = (v0 > pv1) || (v0 == pv1 && i0 < pi1);
        v1 = t1 ? v0 : pv1; i1 = t1 ? i0 : pi1;
        v0 = pv0; i0 = pi0;
    } else {
        bool t1 = (pv0 > v1) || (pv0 == v1 && pi0 < i1);
        if (t1) { v1 = pv0; i1 = pi0; }
    }
}

// Barrier-free main loop: each wave loads its OWN A fragments straight from
// global (L1-hot: the 4 waves of a block share the same 8 KB x-tile per kc)
// and splits in-register. No LDS, no __syncthreads, no vmcnt(0) drain in the
// K-loop -> waves free-run and software-pipeline independently.
// launch_bounds(256,4): 128-VGPR budget for the ~100-reg live set (R2 lesson:
// tighter caps spill -> 400 MB scratch traffic; watch WRITE_SIZE).
__global__ void __launch_bounds__(256, 4) router_kernel(
        const float* __restrict__ x, const short* __restrict__ wp,
        const float* __restrict__ eps, float* __restrict__ out) {
    // LDS only used by the epilogue: noisy[64][66] fp32 = 16896 B.
    __shared__ __align__(16) float noisy[BM * 66];
    __shared__ float4 rowout[BM];

    const int tid    = threadIdx.x;
    const int lane   = tid & 63;
    const int wv     = tid >> 6;      // wave 0..3 -> col group
    const int lane16 = lane & 15;
    const int quad   = lane >> 4;
    const int blockM = blockIdx.x * BM;

    // wave's expert columns: route col_r, noise col_r+64 in packed w
    const int col_r = wv * 16 + lane16;

    // per-lane A base: row = mi*16 + lane16, k = kc*32 + quad*8 + (0..7)
    const float* abase = x + (size_t)(blockM + lane16) * DDIM + (quad << 3);

    f32x4 acc[4][2];   // [mi][0]=route, [1]=noise
#pragma unroll
    for (int a = 0; a < 4; ++a) { acc[a][0] = (f32x4)0.0f; acc[a][1] = (f32x4)0.0f; }

#pragma unroll 2
    for (int kc = 0; kc < NK; ++kc) {
        const short* wpc = wp + (size_t)kc * WCHUNK;

        // B fragments for this kc (L2-hot; issued first, latency hidden by split)
        bf16x8 Bf[3][2];
#pragma unroll
        for (int s = 0; s < 3; ++s) {
            Bf[s][0] = *(const bf16x8*)(wpc + s * 4096 + col_r * 32 + quad * 8);
            Bf[s][1] = *(const bf16x8*)(wpc + s * 4096 + (col_r + 64) * 32 + quad * 8);
        }

#pragma unroll
        for (int mi = 0; mi < 4; ++mi) {
            const float* ap = abase + (size_t)(mi * 16) * DDIM + kc * BK;
            f32x4 a0 = *(const f32x4*)ap;
            f32x4 a1 = *(const f32x4*)(ap + 4);
            bf16x8 H, M, L;
            split_pack(a0, a1, H, M, L);
            __builtin_amdgcn_s_setprio(1);
#pragma unroll
            for (int ni = 0; ni < 2; ++ni) {
                f32x4 c = acc[mi][ni];
                // small-terms-first accumulation: lh, hl, mm, mh, hm, hh
                c = __builtin_amdgcn_mfma_f32_16x16x32_bf16(L, Bf[0][ni], c, 0, 0, 0);
                c = __builtin_amdgcn_mfma_f32_16x16x32_bf16(H, Bf[2][ni], c, 0, 0, 0);
                c = __builtin_amdgcn_mfma_f32_16x16x32_bf16(M, Bf[1][ni], c, 0, 0, 0);
                c = __builtin_amdgcn_mfma_f32_16x16x32_bf16(M, Bf[0][ni], c, 0, 0, 0);
                c = __builtin_amdgcn_mfma_f32_16x16x32_bf16(H, Bf[1][ni], c, 0, 0, 0);
                c = __builtin_amdgcn_mfma_f32_16x16x32_bf16(H, Bf[0][ni], c, 0, 0, 0);
                acc[mi][ni] = c;
            }
            __builtin_amdgcn_s_setprio(0);
        }
    }

    // ---------------- Epilogue ----------------
    // C-frag: row = quad*4 + v, col = lane16  [verified]
#pragma unroll
    for (int mi = 0; mi < 4; ++mi)
#pragma unroll
        for (int v = 0; v < 4; ++v) {
            int row = mi * 16 + quad * 4 + v;
            float ev = eps[(size_t)(blockM + row) * NEXP + col_r];
            noisy[row * 66 + col_r] =
                fmaf(ev, softplus_f(acc[mi][1][v]), acc[mi][0][v]);
        }
    __syncthreads();

    // top-2: 4 threads/row scan 16 cols each, merge via shfl_xor(1), shfl_xor(2)
    {
        int row = tid >> 2;
        int sub = tid & 3;
        float v0 = -INFINITY, v1 = -INFINITY;
        int   i0 = 1 << 20,   i1 = 1 << 20;
#pragma unroll
        for (int j = 0; j < 16; ++j) {
            int col = sub * 16 + j;
            float v = noisy[row * 66 + col];
            if (v > v0) { v1 = v0; i1 = i0; v0 = v; i0 = col; }
            else if (v > v1) { v1 = v; i1 = col; }
        }
#pragma unroll
        for (int d = 1; d <= 2; d <<= 1) {
            float pv0 = __shfl_xor(v0, d, 64);
            int   pi0 = __shfl_xor(i0, d, 64);
            float pv1 = __shfl_xor(v1, d, 64);
            int   pi1 = __shfl_xor(i1, d, 64);
            top2_merge(v0, i0, v1, i1, pv0, pi0, pv1, pi1);
        }
        if (sub == 0) {
            float e1  = expf(v1 - v0);
            float inv = 1.0f / (1.0f + e1);
            rowout[row] = make_float4(inv, e1 * inv,
                                      __int_as_float(i0), __int_as_float(i1));
            float* idx_out = out + (size_t)NROWS * NEXP;
            *(float2*)&idx_out[(size_t)(blockM + row) * 2] =
                make_float2((float)i0, (float)i1);
        }
    }
    __syncthreads();

    // coalesced [64][64] output tile write
#pragma unroll
    for (int it = 0; it < 4; ++it) {
        int f  = it * 256 + tid;       // float4 id 0..1023
        int m  = f >> 4;
        int c4 = (f & 15) << 2;
        float4 ro = rowout[m];
        int i0 = __float_as_int(ro.z);
        int i1 = __float_as_int(ro.w);
        float4 o;
        float* op = (float*)&o;
#pragma unroll
        for (int j = 0; j < 4; ++j) {
            int col = c4 + j;
            op[j] = (col == i0) ? ro.x : (col == i1) ? ro.y : 0.0f;
        }
        *(float4*)&out[(size_t)(blockM + m) * NEXP + c4] = o;
    }
}

extern "C" void kernel_launch(void* const* d_in, const int* in_sizes, int n_in,
                              void* d_out, int out_size, void* d_ws, size_t ws_size,
                              hipStream_t stream) {
    const float* x   = (const float*)d_in[0];
    const float* wr  = (const float*)d_in[1];
    const float* wn  = (const float*)d_in[2];
    const float* eps = (const float*)d_in[3];
    float* out = (float*)d_out;
    short* wp  = (short*)d_ws;   // 32 chunks * 12288 shorts = 1.5 MB scratch

    prep_w_kernel<<<dim3(512), dim3(256), 0, stream>>>(wr, wn, wp);
    router_kernel<<<dim3(NROWS / BM), dim3(256), 0, stream>>>(x, wp, eps, out);
}

// Round 5
// 420.925 us; speedup vs baseline: 1.1294x; 1.1294x over previous
//
#include <hip/hip_runtime.h>
#include <math.h>

// Problem constants
#define NROWS 65536
#define DDIM  1024
#define NEXP  64
#define BM    64      // rows per block
#define BK    32      // K chunk (== one MFMA K)
#define NK    (DDIM / BK)
#define LDX   40      // split-plane leading dim in bf16 elements (80 B rows)
#define PLANE (BM * LDX)          // 2560 shorts per split plane
#define WCHUNK 12288  // shorts per k32-chunk of packed w: 3 splits * 128 n * 32 k

typedef short bf16x8 __attribute__((ext_vector_type(8)));
typedef float f32x4  __attribute__((ext_vector_type(4)));

// exact-ish 3-way bf16 split, round-to-nearest (used in one-time w prep)
__device__ __forceinline__ void split3(float x, unsigned short& h,
                                       unsigned short& m, unsigned short& l) {
    unsigned u = __float_as_uint(x);
    unsigned r = u + 0x7FFFu + ((u >> 16) & 1u);
    h = (unsigned short)(r >> 16);
    float hf = __uint_as_float(r & 0xFFFF0000u);
    float r1 = x - hf;
    unsigned u2 = __float_as_uint(r1);
    unsigned r2 = u2 + 0x7FFFu + ((u2 >> 16) & 1u);
    m = (unsigned short)(r2 >> 16);
    float mf = __uint_as_float(r2 & 0xFFFF0000u);
    float r3 = r1 - mf;
    unsigned u3 = __float_as_uint(r3);
    unsigned r4 = u3 + 0x7FFFu + ((u3 >> 16) & 1u);
    l = (unsigned short)(r4 >> 16);
}

// cheap truncation split for the hot x path: x = h + m + l + O(2^-24 x)
__device__ __forceinline__ void split3t(float x, unsigned& h, unsigned& m, unsigned& l) {
    unsigned u = __float_as_uint(x);
    h = u >> 16;
    float r1 = x - __uint_as_float(u & 0xFFFF0000u);
    unsigned u2 = __float_as_uint(r1);
    m = u2 >> 16;
    float r2 = r1 - __uint_as_float(u2 & 0xFFFF0000u);
    l = __float_as_uint(r2) >> 16;
}

__device__ __forceinline__ float softplus_f(float x) {
    return fmaxf(x, 0.0f) + log1pf(expf(-fabsf(x)));
}

// Pack weights: wp[chunk][split][n][32] bf16, n = 0..63 route, 64..127 noise.
__global__ void __launch_bounds__(256) prep_w_kernel(
        const float* __restrict__ wr, const float* __restrict__ wn,
        short* __restrict__ wp) {
    int idx = blockIdx.x * 256 + threadIdx.x;   // 0..131071
    int n = idx >> 10;
    int k = idx & 1023;
    float v = (n < NEXP) ? wr[n * DDIM + k] : wn[(n - NEXP) * DDIM + k];
    unsigned short h, m, l;
    split3(v, h, m, l);
    int base = (k >> 5) * WCHUNK + n * 32 + (k & 31);
    wp[base]        = (short)h;
    wp[base + 4096] = (short)m;
    wp[base + 8192] = (short)l;
}

__device__ __forceinline__ void stage_split(float4 v, short* plane, int row, int kq) {
    const float* vp = (const float*)&v;
    unsigned hs[3][4];
#pragma unroll
    for (int j = 0; j < 4; ++j) split3t(vp[j], hs[0][j], hs[1][j], hs[2][j]);
#pragma unroll
    for (int s = 0; s < 3; ++s) {
        uint2 p;
        p.x = (hs[s][0] & 0xFFFFu) | (hs[s][1] << 16);
        p.y = (hs[s][2] & 0xFFFFu) | (hs[s][3] << 16);
        *(uint2*)(plane + s * PLANE + row * LDX + kq) = p;
    }
}

__device__ __forceinline__ void top2_merge(float& v0, int& i0, float& v1, int& i1,
                                           float pv0, int pi0, float pv1, int pi1) {
    bool t0 = (pv0 > v0) || (pv0 == v0 && pi0 < i0);
    if (t0) {
        bool t1 = (v0 > pv1) || (v0 == pv1 && i0 < pi1);
        v1 = t1 ? v0 : pv1; i1 = t1 ? i0 : pi1;
        v0 = pv0; i0 = pi0;
    } else {
        bool t1 = (pv0 > v1) || (pv0 == v1 && pi0 < i1);
        if (t1) { v1 = pv0; i1 = pi0; }
    }
}

__device__ __forceinline__ void load_bf(const short* wpc, int col_r, int quad,
                                        bf16x8 (&Bf)[3][2]) {
#pragma unroll
    for (int s = 0; s < 3; ++s) {
        Bf[s][0] = *(const bf16x8*)(wpc + s * 4096 + col_r * 32 + quad * 8);
        Bf[s][1] = *(const bf16x8*)(wpc + s * 4096 + (col_r + 64) * 32 + quad * 8);
    }
}

// One pipelined K-step: issue kc+1's B and x loads, run kc's MFMA phase from
// curbuf/Bfc, then split kc+1's x into nxtbuf (overlapped into MFMA gaps by the
// scheduler; x-load latency hidden under the MFMA phase), then one barrier.
// Buffer safety: nxtbuf was last READ at kc-1 (before barrier kc-1); reads of
// it at kc+1 happen after this barrier. One barrier per kc total.
__device__ __forceinline__ void k_step(
        const float* xp0, const float* xp1, const short* __restrict__ wp,
        short* curbuf, short* nxtbuf,
        bf16x8 (&Bfc)[3][2], bf16x8 (&Bfn)[3][2],
        f32x4 (&acc)[4][2],
        int kc, int srow0, int skq, int lane16, int quad, int col_r) {
    const int kn = kc + 1;
    float4 xv0, xv1;
    if (kn < NK) {
        load_bf(wp + (size_t)kn * WCHUNK, col_r, quad, Bfn);
        xv0 = *(const float4*)(xp0 + (size_t)kn * BK);
        xv1 = *(const float4*)(xp1 + (size_t)kn * BK);
    }

#pragma unroll
    for (int mi = 0; mi < 4; ++mi) {
        bf16x8 Af[3];
#pragma unroll
        for (int s = 0; s < 3; ++s)
            Af[s] = *(const bf16x8*)(curbuf + s * PLANE +
                      (mi * 16 + lane16) * LDX + quad * 8);
        __builtin_amdgcn_s_setprio(1);
#pragma unroll
        for (int ni = 0; ni < 2; ++ni) {
            f32x4 c = acc[mi][ni];
            // small-terms-first accumulation: lh, hl, mm, mh, hm, hh
            c = __builtin_amdgcn_mfma_f32_16x16x32_bf16(Af[2], Bfc[0][ni], c, 0, 0, 0);
            c = __builtin_amdgcn_mfma_f32_16x16x32_bf16(Af[0], Bfc[2][ni], c, 0, 0, 0);
            c = __builtin_amdgcn_mfma_f32_16x16x32_bf16(Af[1], Bfc[1][ni], c, 0, 0, 0);
            c = __builtin_amdgcn_mfma_f32_16x16x32_bf16(Af[1], Bfc[0][ni], c, 0, 0, 0);
            c = __builtin_amdgcn_mfma_f32_16x16x32_bf16(Af[0], Bfc[1][ni], c, 0, 0, 0);
            c = __builtin_amdgcn_mfma_f32_16x16x32_bf16(Af[0], Bfc[0][ni], c, 0, 0, 0);
            acc[mi][ni] = c;
        }
        __builtin_amdgcn_s_setprio(0);
    }

    if (kn < NK) {
        stage_split(xv0, nxtbuf, srow0,      skq);
        stage_split(xv1, nxtbuf, srow0 + 32, skq);
    }
    __syncthreads();
}

// launch_bounds(256,4): 128-VGPR budget for the ~110-reg live set (R2 lesson:
// tighter caps spill; canary = WRITE_SIZE jump). Occupancy is grid-limited at
// 4 blocks/CU; phase overlap comes from the in-loop pipeline, not occupancy.
__global__ void __launch_bounds__(256, 4) router_kernel(
        const float* __restrict__ x, const short* __restrict__ wp,
        const float* __restrict__ eps, float* __restrict__ out) {
    // Double-buffered split planes: 2 bufs x 3 splits x [64][40] bf16 = 30720 B.
    // Epilogue reuses the same region as noisy[64][66] fp32 = 16896 B.
    __shared__ __align__(16) char smem[2 * 3 * PLANE * 2];
    __shared__ float4 rowout[BM];
    short* xs = (short*)smem;

    const int tid    = threadIdx.x;
    const int lane   = tid & 63;
    const int wv     = tid >> 6;      // wave 0..3 -> col group
    const int lane16 = lane & 15;
    const int quad   = lane >> 4;
    const int blockM = blockIdx.x * BM;

    // staging coords: thread covers (srow0, skq) and (srow0+32, skq)
    const int srow0 = tid >> 3;           // 0..31
    const int skq   = (tid & 7) << 2;     // 0,4,..28
    const float* xp0 = x + (size_t)(blockM + srow0) * DDIM + skq;
    const float* xp1 = xp0 + (size_t)32 * DDIM;

    // wave's expert columns: route col_r, noise col_r+64 in packed w
    const int col_r = wv * 16 + lane16;

    short* bufA = xs;
    short* bufB = xs + 3 * PLANE;

    f32x4 acc[4][2];   // [mi][0]=route, [1]=noise
#pragma unroll
    for (int a = 0; a < 4; ++a) { acc[a][0] = (f32x4)0.0f; acc[a][1] = (f32x4)0.0f; }

    // ---- prologue: stage kc=0 into bufA, preload Bf for kc=0 ----
    bf16x8 BfA[3][2], BfB[3][2];
    {
        float4 xv0 = *(const float4*)xp0;
        float4 xv1 = *(const float4*)xp1;
        stage_split(xv0, bufA, srow0,      skq);
        stage_split(xv1, bufA, srow0 + 32, skq);
    }
    load_bf(wp, col_r, quad, BfA);
    __syncthreads();

    // ---- pipelined main loop: explicit even/odd bodies (static buffers) ----
    for (int kc2 = 0; kc2 < NK; kc2 += 2) {
        k_step(xp0, xp1, wp, bufA, bufB, BfA, BfB, acc,
               kc2,     srow0, skq, lane16, quad, col_r);
        k_step(xp0, xp1, wp, bufB, bufA, BfB, BfA, acc,
               kc2 + 1, srow0, skq, lane16, quad, col_r);
    }
    // final k_step's __syncthreads protects smem reuse below.

    // ---------------- Epilogue ----------------
    // C-frag: row = quad*4 + v, col = lane16  [verified]
    float* noisy = (float*)smem;   // [64][66]
#pragma unroll
    for (int mi = 0; mi < 4; ++mi)
#pragma unroll
        for (int v = 0; v < 4; ++v) {
            int row = mi * 16 + quad * 4 + v;
            float ev = eps[(size_t)(blockM + row) * NEXP + col_r];
            noisy[row * 66 + col_r] =
                fmaf(ev, softplus_f(acc[mi][1][v]), acc[mi][0][v]);
        }
    __syncthreads();

    // top-2: 4 threads/row scan 16 cols each, merge via shfl_xor(1), shfl_xor(2)
    {
        int row = tid >> 2;
        int sub = tid & 3;
        float v0 = -INFINITY, v1 = -INFINITY;
        int   i0 = 1 << 20,   i1 = 1 << 20;
#pragma unroll
        for (int j = 0; j < 16; ++j) {
            int col = sub * 16 + j;
            float v = noisy[row * 66 + col];
            if (v > v0) { v1 = v0; i1 = i0; v0 = v; i0 = col; }
            else if (v > v1) { v1 = v; i1 = col; }
        }
#pragma unroll
        for (int d = 1; d <= 2; d <<= 1) {
            float pv0 = __shfl_xor(v0, d, 64);
            int   pi0 = __shfl_xor(i0, d, 64);
            float pv1 = __shfl_xor(v1, d, 64);
            int   pi1 = __shfl_xor(i1, d, 64);
            top2_merge(v0, i0, v1, i1, pv0, pi0, pv1, pi1);
        }
        if (sub == 0) {
            float e1  = expf(v1 - v0);
            float inv = 1.0f / (1.0f + e1);
            rowout[row] = make_float4(inv, e1 * inv,
                                      __int_as_float(i0), __int_as_float(i1));
            float* idx_out = out + (size_t)NROWS * NEXP;
            *(float2*)&idx_out[(size_t)(blockM + row) * 2] =
                make_float2((float)i0, (float)i1);
        }
    }
    __syncthreads();

    // coalesced [64][64] output tile write
#pragma unroll
    for (int it = 0; it < 4; ++it) {
        int f  = it * 256 + tid;       // float4 id 0..1023
        int m  = f >> 4;
        int c4 = (f & 15) << 2;
        float4 ro = rowout[m];
        int i0 = __float_as_int(ro.z);
        int i1 = __float_as_int(ro.w);
        float4 o;
        float* op = (float*)&o;
#pragma unroll
        for (int j = 0; j < 4; ++j) {
            int col = c4 + j;
            op[j] = (col == i0) ? ro.x : (col == i1) ? ro.y : 0.0f;
        }
        *(float4*)&out[(size_t)(blockM + m) * NEXP + c4] = o;
    }
}

extern "C" void kernel_launch(void* const* d_in, const int* in_sizes, int n_in,
                              void* d_out, int out_size, void* d_ws, size_t ws_size,
                              hipStream_t stream) {
    const float* x   = (const float*)d_in[0];
    const float* wr  = (const float*)d_in[1];
    const float* wn  = (const float*)d_in[2];
    const float* eps = (const float*)d_in[3];
    float* out = (float*)d_out;
    short* wp  = (short*)d_ws;   // 32 chunks * 12288 shorts = 1.5 MB scratch

    prep_w_kernel<<<dim3(512), dim3(256), 0, stream>>>(wr, wn, wp);
    router_kernel<<<dim3(NROWS / BM), dim3(256), 0, stream>>>(x, wp, eps, out);
}